// Round 16
// baseline (237.156 us; speedup 1.0000x reference)
//
#include <hip/hip_runtime.h>
#include <hip/hip_fp8.h>

// CausalConv3dFP8 round 16: attack the LDS-throughput wall. Wave tile 128co x 64w
// (ct4 x nf2, acc 128 AGPR): each B-fragment pair feeds 8 MFMAs -> 512 B/MFMA
// (was 1024) -> LDS B-read rate 35% of ceiling at full MFMA rate. Block = 4 waves
// at hr0..3 (128co x 64w x 4h); all waves share identical A-frags (L1 broadcast).
// Single-parity loads, lean arch-VGPR; launch_bounds(256,2) = 2 waves/SIMD.
// xq layout: [b][d4][hp194][ci32 grp 4][wp322][32B]
// wpk layout: [tap27][cc2][ct4][lane64][32B]

using f32x16 = __attribute__((ext_vector_type(16))) float;
using i32x8 = __attribute__((ext_vector_type(8))) int;
using i32x4 = __attribute__((ext_vector_type(4))) int;
typedef long long i64;
struct alignas(16) L2v { i64 x, y; };

namespace {
constexpr int Cc = 128, Dd = 4, Hh = 192, Ww = 320;
constexpr int HP = 194, WP = 322;
constexpr int NTAP = 27;
constexpr size_t PLANE = (size_t)4 * WP * 32;               // 41,216 B per (b,d,h) row-plane
constexpr size_t XQ_BYTES = (size_t)2 * Dd * HP * PLANE;    // 63,967,232
constexpr int ZA = 8 * 2 * 2576;
constexpr int ZB = 8 * 192 * 32;
constexpr int GSTR = WP * 32;                               // 10,304 B per ci32-group
constexpr int HB = 1056;                                    // 66*16 half-plane stride
constexpr int KDSTR = 9 * 2 * 4 * 64 * 32;                  // 147,456 B per kd in wpk
constexpr int NQX = 5 * 192 * 8;
constexpr int NZP = (ZA + ZB + 255) / 256;
constexpr int NWP = (Cc * Cc * NTAP + 255) / 256;
}

__global__ __launch_bounds__(256) void prep_kernel(const float* __restrict__ x,
                                                   const float* __restrict__ w,
                                                   unsigned char* __restrict__ xq,
                                                   unsigned char* __restrict__ wpk) {
  const int id = blockIdx.x;
  const int tid = threadIdx.x;
  if (id < NQX) {
    __shared__ unsigned char lt[64 * 136];
    const int wx = id % 5;
    const int h = (id / 5) % 192;
    const int bd = id / 960;
    const int b = bd >> 2, d = bd & 3;
    const int w0 = wx * 64;
    const int wl = tid & 63, cig = tid >> 6;
    const size_t cstr = (size_t)Dd * Hh * Ww;
    const float* xp = x + (((size_t)b * Cc * Dd + d) * Hh + h) * Ww + w0 + wl;
    #pragma unroll 4
    for (int i = 0; i < 32; ++i) {
      int ci = cig * 32 + i;
      __hip_fp8_e4m3 q(xp[ci * cstr]);
      lt[wl * 136 + ci] = q.__x;
    }
    __syncthreads();
    unsigned char* plane = xq + ((size_t)(b * Dd + d) * HP + h + 1) * PLANE;
    int g = tid >> 6, ww = tid & 63;
    const unsigned char* src = lt + ww * 136 + g * 32;
    i64 a0 = *(const i64*)(src), a1 = *(const i64*)(src + 8);
    i64 a2 = *(const i64*)(src + 16), a3 = *(const i64*)(src + 24);
    unsigned char* dst = plane + (size_t)g * GSTR + (size_t)(w0 + 1 + ww) * 32;
    *(L2v*)dst = L2v{a0, a1};
    *(L2v*)(dst + 16) = L2v{a2, a3};
  } else if (id < NQX + NZP) {
    int i = (id - NQX) * 256 + tid;
    if (i < ZA) {
      int bd = i / (2 * 2576);
      int r = i - bd * (2 * 2576);
      int hsel = r / 2576, seg = r - hsel * 2576;
      L2v z{0, 0};
      *(L2v*)(xq + ((size_t)bd * HP + (hsel ? 193 : 0)) * PLANE + (size_t)seg * 16) = z;
    } else if (i < ZA + ZB) {
      int j = i - ZA;
      int bd = j / (192 * 32);
      int r = j - bd * (192 * 32);
      int h = r / 32 + 1;
      int t = r & 31;
      int g = t >> 3, s2 = t & 7;
      int wsel = s2 >> 2, part = s2 & 3;
      *(i64*)(xq + ((size_t)bd * HP + h) * PLANE + (size_t)g * GSTR
              + (size_t)(wsel ? 321 : 0) * 32 + part * 8) = 0;
    }
  } else {
    int idx = (id - NQX - NZP) * 256 + tid;
    if (idx < Cc * Cc * NTAP) {
      int tap = idx % NTAP;
      int t = idx / NTAP;
      int ci = t % Cc, co = t / Cc;
      int cc = ci >> 6, cq = co >> 5;
      int lane = (((ci >> 5) & 1) << 5) | (co & 31);
      __hip_fp8_e4m3 q(w[idx]);
      wpk[((((size_t)tap * 2 + cc) * 4 + cq) * 64 + lane) * 32 + (ci & 31)] = q.__x;
    }
  }
}

__global__ __launch_bounds__(256, 2) void conv_mfma(const unsigned char* __restrict__ xq,
                                                    const unsigned char* __restrict__ wpk,
                                                    float* __restrict__ out) {
  __shared__ unsigned char lb[6 * 4 * 2 * HB];     // [hrow6][g4][half2][66w][16B] = 50,688 B
  const int tid = threadIdx.x;
  const int lane = tid & 63;
  const int hr = tid >> 6;                         // wave: h-row 0..3 (full 128 co each)
  const int l31 = lane & 31, chalf = lane >> 5;
  // ---- bijective XCD h-band swizzle: 1920 blocks, 240/XCD ----
  const int id = blockIdx.x;
  const int xcd = id & 7, j = id >> 3;
  const int h0l = j / 40, rem = j - h0l * 40;
  const int z = rem / 5, wx = rem - z * 5;
  const int b = z >> 2, dout = z & 3;
  const int h0 = (xcd * 6 + h0l) * 4;              // 4 output h-rows per block
  const int w0 = wx * 64;
  const int kdmin = dout >= 2 ? 0 : 2 - dout;

  const long imgstep = (long)HP * PLANE;
  const long img0 = (long)(b * Dd + dout - 2) * imgstep;
  const unsigned char* vbase = wpk + lane * 32;    // A: same for all 4 waves (L1 broadcast)

  // B read bases per kw; row(hrow)=hr+kh via +kh*8448 imm, cc via +4224, nf via +512
  const unsigned char* bb[3];
  #pragma unroll
  for (int kw = 0; kw < 3; ++kw)
    bb[kw] = lb + hr * 8448 + chalf * 2112 + (l31 + kw) * 16;

  f32x16 acc[4][2];                                // [ct][nf] = 128 AGPR
  #pragma unroll
  for (int a = 0; a < 4; ++a)
    #pragma unroll
    for (int n = 0; n < 2; ++n)
      #pragma unroll
      for (int r = 0; r < 16; ++r) acc[a][n][r] = 0.f;

  for (int kd = kdmin; kd < 3; ++kd) {
    __syncthreads();
    // ---- stage [hrow6][g4][66w] x 32B for this kd (1584 units) ----
    const unsigned char* img = xq + img0 + (long)kd * imgstep;
    for (int u = tid; u < 1584; u += 256) {
      int w = u % 66, rest = u / 66;               // rest = hrow*4+g, 0..23
      int g = rest & 3, hrow = rest >> 2;
      const unsigned char* src = img + (size_t)(h0 + hrow) * PLANE
          + (size_t)g * GSTR + (size_t)(w0 + w) * 32;
      L2v lo = *(const L2v*)src;
      L2v hi = *(const L2v*)(src + 16);
      unsigned char* base = lb + rest * 2112 + w * 16;
      *(L2v*)(base) = lo;                          // half 0
      *(L2v*)(base + HB) = hi;                     // half 1
    }
    __syncthreads();

    const unsigned char* wkd = vbase + (size_t)kd * KDSTR;
    __builtin_amdgcn_s_setprio(1);
    #pragma unroll
    for (int kh = 0; kh < 3; ++kh)
      #pragma unroll
      for (int cc = 0; cc < 2; ++cc)
        #pragma unroll
        for (int kw = 0; kw < 3; ++kw) {
          // ---- A: 4 ct x 32B (identical across waves -> L1) ----
          i32x8 av[4];
          #pragma unroll
          for (int ct = 0; ct < 4; ++ct)
            av[ct] = *(const i32x8*)(wkd + (kh * 3 + kw) * 16384 + cc * 8192 + ct * 2048);
          // ---- B: 2 nf x (lo+hi) = 4 ds_read_b128, feeds 8 MFMAs ----
          i32x8 bv[2];
          #pragma unroll
          for (int nf = 0; nf < 2; ++nf) {
            const int off = kh * 8448 + cc * 4224 + nf * 512;
            i32x4 blo = *(const i32x4*)(bb[kw] + off);
            i32x4 bhi = *(const i32x4*)(bb[kw] + off + HB);
            bv[nf] = __builtin_shufflevector(blo, bhi, 0, 1, 2, 3, 4, 5, 6, 7);
          }
          #pragma unroll
          for (int nf = 0; nf < 2; ++nf)
            #pragma unroll
            for (int ct = 0; ct < 4; ++ct)
              acc[ct][nf] = __builtin_amdgcn_mfma_scale_f32_32x32x64_f8f6f4(
                  av[ct], bv[nf], acc[ct][nf], 0, 0, 0, 127, 0, 127);
        }
    __builtin_amdgcn_s_setprio(0);
  }

  // ---- epilogue: col=l31 -> w, row=(reg&3)+8*(reg>>2)+4*chalf -> cout ----
  #pragma unroll
  for (int ct = 0; ct < 4; ++ct)
    #pragma unroll
    for (int nf = 0; nf < 2; ++nf) {
      int ww = w0 + nf * 32 + l31;
      #pragma unroll
      for (int reg = 0; reg < 16; ++reg) {
        int co = ct * 32 + (reg & 3) + 8 * (reg >> 2) + 4 * chalf;
        out[(((size_t)b * Cc + co) * Dd + dout) * (size_t)(Hh * Ww)
            + (size_t)(h0 + hr) * Ww + ww] = acc[ct][nf][reg];
      }
    }
}

extern "C" void kernel_launch(void* const* d_in, const int* in_sizes, int n_in,
                              void* d_out, int out_size, void* d_ws, size_t ws_size,
                              hipStream_t stream) {
  const float* x = (const float*)d_in[0];
  const float* w = (const float*)d_in[1];
  unsigned char* xq = (unsigned char*)d_ws;
  unsigned char* wpk = xq + XQ_BYTES;              // 442,368 B
  float* out = (float*)d_out;

  prep_kernel<<<dim3(NQX + NZP + NWP), 256, 0, stream>>>(x, w, xq, wpk);
  conv_mfma<<<dim3(1920), 256, 0, stream>>>(xq, wpk, out);
}

// Round 18
// 223.690 us; speedup vs baseline: 1.0602x; 1.0602x over previous
//
#include <hip/hip_runtime.h>
#include <hip/hip_fp8.h>

// CausalConv3dFP8 round 18: r17 (gll region-split staging) with the tail fixed:
// 4 uniform gll iterations (1024 units) + exec-masked tail (tid<32, 32 units) —
// satisfies gll's wave-uniform-base + lane*16 LDS write contract (rule 21/m104).
//   LO region: lb[u*16] (ci 0..15 of unit u), HI: lb[16896 + u*16] (ci 16..31).
// B reads: LO/HI + ((hr+kh)*4 + cc*2 + chalf)*1056 + (l31+kw)*16 + nf*512, imm.
// kd-skip, bijective XCD h-band swizzle, setprio. acc 64 AGPR, 4 blocks/CU.
// xq layout: [b][d4][hp194][ci32 grp 4][wp322][32B]
// wpk layout: [tap27][cc2][cq4][lane64][32B]

using f32x16 = __attribute__((ext_vector_type(16))) float;
using i32x8 = __attribute__((ext_vector_type(8))) int;
using i32x4 = __attribute__((ext_vector_type(4))) int;
typedef long long i64;
struct alignas(16) L2v { i64 x, y; };

namespace {
constexpr int Cc = 128, Dd = 4, Hh = 192, Ww = 320;
constexpr int HP = 194, WP = 322;
constexpr int NTAP = 27;
constexpr size_t PLANE = (size_t)4 * WP * 32;               // 41,216 B per (b,d,h) row-plane
constexpr size_t XQ_BYTES = (size_t)2 * Dd * HP * PLANE;    // 63,967,232
constexpr int ZA = 8 * 2 * 2576;
constexpr int ZB = 8 * 192 * 32;
constexpr int GSTR = WP * 32;                               // 10,304 B per ci32-group
constexpr int REG = 16896;                                  // 1056*16: HI-LO region offset
constexpr int KDSTR = 9 * 2 * 4 * 64 * 32;                  // 147,456 B per kd in wpk
constexpr int NQX = 5 * 192 * 8;
constexpr int NZP = (ZA + ZB + 255) / 256;
constexpr int NWP = (Cc * Cc * NTAP + 255) / 256;
}

__global__ __launch_bounds__(256) void prep_kernel(const float* __restrict__ x,
                                                   const float* __restrict__ w,
                                                   unsigned char* __restrict__ xq,
                                                   unsigned char* __restrict__ wpk) {
  const int id = blockIdx.x;
  const int tid = threadIdx.x;
  if (id < NQX) {
    __shared__ unsigned char lt[64 * 136];
    const int wx = id % 5;
    const int h = (id / 5) % 192;
    const int bd = id / 960;
    const int b = bd >> 2, d = bd & 3;
    const int w0 = wx * 64;
    const int wl = tid & 63, cig = tid >> 6;
    const size_t cstr = (size_t)Dd * Hh * Ww;
    const float* xp = x + (((size_t)b * Cc * Dd + d) * Hh + h) * Ww + w0 + wl;
    #pragma unroll 4
    for (int i = 0; i < 32; ++i) {
      int ci = cig * 32 + i;
      __hip_fp8_e4m3 q(xp[ci * cstr]);
      lt[wl * 136 + ci] = q.__x;
    }
    __syncthreads();
    unsigned char* plane = xq + ((size_t)(b * Dd + d) * HP + h + 1) * PLANE;
    int g = tid >> 6, ww = tid & 63;
    const unsigned char* src = lt + ww * 136 + g * 32;
    i64 a0 = *(const i64*)(src), a1 = *(const i64*)(src + 8);
    i64 a2 = *(const i64*)(src + 16), a3 = *(const i64*)(src + 24);
    unsigned char* dst = plane + (size_t)g * GSTR + (size_t)(w0 + 1 + ww) * 32;
    *(L2v*)dst = L2v{a0, a1};
    *(L2v*)(dst + 16) = L2v{a2, a3};
  } else if (id < NQX + NZP) {
    int i = (id - NQX) * 256 + tid;
    if (i < ZA) {
      int bd = i / (2 * 2576);
      int r = i - bd * (2 * 2576);
      int hsel = r / 2576, seg = r - hsel * 2576;
      L2v z{0, 0};
      *(L2v*)(xq + ((size_t)bd * HP + (hsel ? 193 : 0)) * PLANE + (size_t)seg * 16) = z;
    } else if (i < ZA + ZB) {
      int j = i - ZA;
      int bd = j / (192 * 32);
      int r = j - bd * (192 * 32);
      int h = r / 32 + 1;
      int t = r & 31;
      int g = t >> 3, s2 = t & 7;
      int wsel = s2 >> 2, part = s2 & 3;
      *(i64*)(xq + ((size_t)bd * HP + h) * PLANE + (size_t)g * GSTR
              + (size_t)(wsel ? 321 : 0) * 32 + part * 8) = 0;
    }
  } else {
    int idx = (id - NQX - NZP) * 256 + tid;
    if (idx < Cc * Cc * NTAP) {
      int tap = idx % NTAP;
      int t = idx / NTAP;
      int ci = t % Cc, co = t / Cc;
      int cc = ci >> 6, cq = co >> 5;
      int lane = (((ci >> 5) & 1) << 5) | (co & 31);
      __hip_fp8_e4m3 q(w[idx]);
      wpk[((((size_t)tap * 2 + cc) * 4 + cq) * 64 + lane) * 32 + (ci & 31)] = q.__x;
    }
  }
}

__device__ __forceinline__ void gll16(const unsigned char* g, unsigned char* l) {
  __builtin_amdgcn_global_load_lds(
      (const __attribute__((address_space(1))) void*)g,
      (__attribute__((address_space(3))) void*)l, 16, 0, 0);
}

__global__ __launch_bounds__(256, 4) void conv_mfma(const unsigned char* __restrict__ xq,
                                                    const unsigned char* __restrict__ wpk,
                                                    float* __restrict__ out) {
  __shared__ unsigned char lb[2 * REG];            // LO[1056][16] + HI[1056][16] = 33,792 B
  const int tid = threadIdx.x;
  const int lane = tid & 63, wv = tid >> 6;
  const int l31 = lane & 31, chalf = lane >> 5;
  const int hr = wv >> 1, ch = wv & 1;             // wave: h-row, cout-half
  // ---- bijective XCD h-band swizzle ----
  const int id = blockIdx.x;
  const int xcd = id & 7, j = id >> 3;
  const int h0l = j / 40, rem = j - h0l * 40;
  const int z = rem / 5, wx = rem - z * 5;
  const int b = z >> 2, dout = z & 3;
  const int h0 = (xcd * 12 + h0l) * 2;
  const int w0 = wx * 64;
  const int kdmin = dout >= 2 ? 0 : 2 - dout;

  const long imgstep = (long)HP * PLANE;
  const long img0 = (long)(b * Dd + dout - 2) * imgstep;
  const unsigned char* vbase = wpk + ch * 4096 + lane * 32;

  // ---- staging descriptors: units 0..1023 uniform; 1024..1055 via masked tail ----
  size_t soff[4];
  int ldst[4];
  #pragma unroll
  for (int k = 0; k < 4; ++k) {
    int u = tid + k * 256;
    int w = u % 66, rest = u / 66;
    int g = rest & 3, hrow = rest >> 2;
    soff[k] = (size_t)(h0 + hrow) * PLANE + (size_t)g * GSTR + (size_t)(w0 + w) * 32;
    ldst[k] = u * 16;
  }
  size_t soff4;
  int ldst4;
  {
    int u = 1024 + (tid & 31);                     // only lanes 0..31 of wave 0 use this
    int w = u % 66, rest = u / 66;
    int g = rest & 3, hrow = rest >> 2;
    soff4 = (size_t)(h0 + hrow) * PLANE + (size_t)g * GSTR + (size_t)(w0 + w) * 32;
    ldst4 = u * 16;
  }

  // B read bases per kw (LO region; HI via +REG imm)
  const unsigned char* bb[3];
  #pragma unroll
  for (int kw = 0; kw < 3; ++kw)
    bb[kw] = lb + (hr * 4 + chalf) * 1056 + (l31 + kw) * 16;

  f32x16 acc[2][2];                                // [ct][nf] = 64 AGPR
  #pragma unroll
  for (int a = 0; a < 2; ++a)
    #pragma unroll
    for (int n = 0; n < 2; ++n)
      #pragma unroll
      for (int r = 0; r < 16; ++r) acc[a][n][r] = 0.f;

  for (int kd = kdmin; kd < 3; ++kd) {
    __syncthreads();                               // prev compute done; buffer free
    // ---- stage via global_load_lds into LO/HI regions ----
    const unsigned char* img = xq + img0 + (long)kd * imgstep;
    #pragma unroll
    for (int k = 0; k < 4; ++k) {
      gll16(img + soff[k], lb + ldst[k]);
      gll16(img + soff[k] + 16, lb + REG + ldst[k]);
    }
    if (tid < 32) {                                // exec-masked tail: units 1024..1055
      gll16(img + soff4, lb + ldst4);
      gll16(img + soff4 + 16, lb + REG + ldst4);
    }
    __syncthreads();                               // drains gll vmcnt for all waves

    const unsigned char* wkd = vbase + (size_t)kd * KDSTR;
    __builtin_amdgcn_s_setprio(1);
    #pragma unroll
    for (int kh = 0; kh < 3; ++kh)
      #pragma unroll
      for (int cc = 0; cc < 2; ++cc)
        #pragma unroll
        for (int kw = 0; kw < 3; ++kw) {
          i32x8 av[2];
          #pragma unroll
          for (int ct = 0; ct < 2; ++ct)
            av[ct] = *(const i32x8*)(wkd + (kh * 3 + kw) * 16384 + cc * 8192 + ct * 2048);
          #pragma unroll
          for (int nf = 0; nf < 2; ++nf) {
            const int off = kh * 4224 + cc * 2112 + nf * 512;
            i32x4 blo = *(const i32x4*)(bb[kw] + off);
            i32x4 bhi = *(const i32x4*)(bb[kw] + off + REG);
            i32x8 bv = __builtin_shufflevector(blo, bhi, 0, 1, 2, 3, 4, 5, 6, 7);
            #pragma unroll
            for (int ct = 0; ct < 2; ++ct)
              acc[ct][nf] = __builtin_amdgcn_mfma_scale_f32_32x32x64_f8f6f4(
                  av[ct], bv, acc[ct][nf], 0, 0, 0, 127, 0, 127);
          }
        }
    __builtin_amdgcn_s_setprio(0);
  }

  // ---- epilogue: col=l31 -> w, row=(reg&3)+8*(reg>>2)+4*chalf -> cout ----
  #pragma unroll
  for (int ct = 0; ct < 2; ++ct)
    #pragma unroll
    for (int nf = 0; nf < 2; ++nf) {
      int ww = w0 + nf * 32 + l31;
      #pragma unroll
      for (int reg = 0; reg < 16; ++reg) {
        int co = ch * 64 + ct * 32 + (reg & 3) + 8 * (reg >> 2) + 4 * chalf;
        out[(((size_t)b * Cc + co) * Dd + dout) * (size_t)(Hh * Ww)
            + (size_t)(h0 + hr) * Ww + ww] = acc[ct][nf][reg];
      }
    }
}

extern "C" void kernel_launch(void* const* d_in, const int* in_sizes, int n_in,
                              void* d_out, int out_size, void* d_ws, size_t ws_size,
                              hipStream_t stream) {
  const float* x = (const float*)d_in[0];
  const float* w = (const float*)d_in[1];
  unsigned char* xq = (unsigned char*)d_ws;
  unsigned char* wpk = xq + XQ_BYTES;              // 442,368 B
  float* out = (float*)d_out;

  prep_kernel<<<dim3(NQX + NZP + NWP), 256, 0, stream>>>(x, w, xq, wpk);
  conv_mfma<<<dim3(3840), 256, 0, stream>>>(xq, wpk, out);
}